// Round 2
// baseline (120.719 us; speedup 1.0000x reference)
//
#include <hip/hip_runtime.h>

// TopDownHTMM fused forward, v2.
// 512 blocks = (tree, g); BLOCK=512 threads, one thread per level-9 node.
// Levels 0..8 staged in LDS (1023 slots incl. L9 ratio handoff); levels 9-10
// (75% of nodes) fully in registers per thread, no syncs.
// Slot lifecycle per node: prior -> ratio(beta/prior) -> eps.

#define NTREES 64
#define DEPTH  10
#define C      8
#define M      32
#define G      8
#define NPT    2047
#define PAD    9            // floats per node slot (odd -> conflict-light)
#define BLOCK  512
#define LNODES 1023         // nodes of levels 0..9

__device__ __forceinline__ float frcp(float v) { return __builtin_amdgcn_rcpf(v); }

__global__ __launch_bounds__(BLOCK, 4)
void htmm_kernel(const float* __restrict__ A,   // (C,C,G)
                 const float* __restrict__ B,   // (C,M,G)
                 const float* __restrict__ Pi,  // (C,G)
                 const int*   __restrict__ x,   // (DIM,)
                 float* __restrict__ out)       // (NTREES,G)
{
    __shared__ float buf[LNODES * PAD];         // 36,828 B
    __shared__ float sA[C][C], sAL[C][C];       // softmax_i A ; sA*log(sA)
    __shared__ float sB[C][M], lgB[C][M];
    __shared__ float spi[C],  lgpi[C];
    __shared__ float bls[C];                    // per-row logsumexp of B
    __shared__ float red8[BLOCK / 64];

    const int b   = blockIdx.x;
    const int t   = b >> 3;
    const int g   = b & 7;
    const int tid = threadIdx.x;
    const int base = t * NPT;

    // ---------------- phase 1: row stats ----------------
    if (tid < C) {                               // A column j: softmax over i
        const int j = tid;
        float w[C]; float mx = -1e30f;
        #pragma unroll
        for (int i = 0; i < C; ++i) { w[i] = A[(i*C + j)*G + g]; mx = fmaxf(mx, w[i]); }
        float s = 0.f; float e[C];
        #pragma unroll
        for (int i = 0; i < C; ++i) { e[i] = expf(w[i] - mx); s += e[i]; }
        const float inv = 1.f / s, ls = logf(s);
        #pragma unroll
        for (int i = 0; i < C; ++i) {
            const float sm = e[i] * inv;
            sA[i][j]  = sm;
            sAL[i][j] = sm * ((w[i] - mx) - ls);
        }
    } else if (tid == 8) {                       // Pi softmax
        float w[C]; float mx = -1e30f;
        #pragma unroll
        for (int c = 0; c < C; ++c) { w[c] = Pi[c*G + g]; mx = fmaxf(mx, w[c]); }
        float s = 0.f; float e[C];
        #pragma unroll
        for (int c = 0; c < C; ++c) { e[c] = expf(w[c] - mx); s += e[c]; }
        const float inv = 1.f / s, ls = logf(s);
        #pragma unroll
        for (int c = 0; c < C; ++c) { spi[c] = e[c]*inv; lgpi[c] = (w[c]-mx) - ls; }
    } else if (tid >= 64 && tid < 64 + C) {      // B row c: logsumexp
        const int c = tid - 64;
        float mx = -1e30f;
        for (int m = 0; m < M; ++m) mx = fmaxf(mx, B[(c*M + m)*G + g]);
        float s = 0.f;
        for (int m = 0; m < M; ++m) s += expf(B[(c*M + m)*G + g] - mx);
        bls[c] = mx + logf(s);
    }
    __syncthreads();

    // ---------------- phase 2: B softmax wide + root prior ----------------
    if (tid < C * M) {                           // 256 threads: one (c,m) each
        const int c = tid >> 5, m = tid & 31;
        const float d0 = B[(c*M + m)*G + g] - bls[c];
        lgB[c][m] = d0;
        sB[c][m]  = expf(d0);
    }
    if (tid == 320) {
        #pragma unroll
        for (int i = 0; i < C; ++i) buf[i] = spi[i];
    }
    __syncthreads();

    // ---------------- pass 1: prior, LDS levels 1..8 ----------------
    // both children share the same prior -> one matvec per parent
    for (int d = 1; d <= 8; ++d) {
        const int half = 1 << (d - 1);
        if (tid < half) {
            const int u = half - 1 + tid;        // parent (level d-1)
            const int cb = 2*u + 1;
            float p[C];
            #pragma unroll
            for (int j = 0; j < C; ++j) p[j] = buf[u*PAD + j];
            #pragma unroll
            for (int i = 0; i < C; ++i) {
                float acc = 0.f;
                #pragma unroll
                for (int j = 0; j < C; ++j) acc += sA[i][j] * p[j];
                buf[cb*PAD + i]       = acc;
                buf[(cb + 1)*PAD + i] = acc;
            }
        }
        __syncthreads();
    }

    // ---------------- pass 1: subtree (levels 9,10) in registers ----------------
    const int s  = 511 + tid;                    // owned level-9 node (local idx)
    const int xs = x[base + s];
    const int x1 = x[base + 2*s + 1];
    const int x2 = x[base + 2*s + 2];

    float ps[C], pc[C];                          // prior of s; prior of both leaves
    {
        const int pas = 255 + (tid >> 1);
        float pp[C];
        #pragma unroll
        for (int j = 0; j < C; ++j) pp[j] = buf[pas*PAD + j];
        #pragma unroll
        for (int i = 0; i < C; ++i) {
            float a = 0.f;
            #pragma unroll
            for (int j = 0; j < C; ++j) a += sA[i][j] * pp[j];
            ps[i] = a;
        }
        #pragma unroll
        for (int i = 0; i < C; ++i) {
            float a = 0.f;
            #pragma unroll
            for (int j = 0; j < C; ++j) a += sA[i][j] * ps[j];
            pc[i] = a;
        }
    }

    // ---------------- pass 2: subtree beta ratios in registers ----------------
    float rs[C], r1[C], r2[C];
    {
        // leaves: ratio = emit / Z
        float e1[C], e2[C]; float Z1 = 0.f, Z2 = 0.f;
        #pragma unroll
        for (int i = 0; i < C; ++i) {
            e1[i] = sB[i][x1]; Z1 += pc[i] * e1[i];
            e2[i] = sB[i][x2]; Z2 += pc[i] * e2[i];
        }
        const float i1 = frcp(Z1), i2 = frcp(Z2);
        #pragma unroll
        for (int i = 0; i < C; ++i) { r1[i] = e1[i]*i1; r2[i] = e2[i]*i2; }
        // node s
        float Z = 0.f, ep[C];
        #pragma unroll
        for (int j = 0; j < C; ++j) {
            float a1 = 0.f, a2 = 0.f;
            #pragma unroll
            for (int i = 0; i < C; ++i) { a1 += sA[i][j]*r1[i]; a2 += sA[i][j]*r2[i]; }
            ep[j] = sB[j][xs] * (a1 * a2);
            Z += ps[j] * ep[j];
        }
        const float iz = frcp(Z);
        #pragma unroll
        for (int j = 0; j < C; ++j) { rs[j] = ep[j]*iz; buf[s*PAD + j] = rs[j]; }
    }
    __syncthreads();

    // ---------------- pass 2: LDS levels 8..0 ----------------
    for (int d = 8; d >= 0; --d) {
        if (tid < (1 << d)) {
            const int u = (1 << d) - 1 + tid;
            const int c1 = 2*u + 1;
            float rr1[C], rr2[C];
            #pragma unroll
            for (int i = 0; i < C; ++i) { rr1[i] = buf[c1*PAD + i]; rr2[i] = buf[(c1+1)*PAD + i]; }
            const int xu = x[base + u];
            float pr[C], ep[C]; float Z = 0.f;
            #pragma unroll
            for (int j = 0; j < C; ++j) {
                float a1 = 0.f, a2 = 0.f;
                #pragma unroll
                for (int i = 0; i < C; ++i) { a1 += sA[i][j]*rr1[i]; a2 += sA[i][j]*rr2[i]; }
                ep[j] = sB[j][xu] * (a1 * a2);
                pr[j] = buf[u*PAD + j];
                Z += pr[j] * ep[j];
            }
            const float iz = frcp(Z);
            if (d) {
                #pragma unroll
                for (int j = 0; j < C; ++j) buf[u*PAD + j] = ep[j]*iz;     // ratio
            } else {
                #pragma unroll
                for (int j = 0; j < C; ++j) buf[j] = pr[j]*ep[j]*iz;       // eps root
            }
        }
        __syncthreads();
    }

    // ---------------- pass 3: eps + likelihood ----------------
    // child contribution: given ratio r, parent eps epa, symbol xv:
    // recompute t_beta, fused t_eps reductions; returns lik term, optional eps out.
    auto child_node = [&](const float* r, const float* epa, int xv, float* eout) -> float {
        float f[C];
        #pragma unroll
        for (int j = 0; j < C; ++j) {
            float tb = 0.f;
            #pragma unroll
            for (int i = 0; i < C; ++i) tb += sA[i][j] * r[i];
            f[j] = epa[j] * frcp(tb);
        }
        float S = 0.f, likA = 0.f, num[C];
        #pragma unroll
        for (int i = 0; i < C; ++i) {
            float a = 0.f, la = 0.f;
            #pragma unroll
            for (int j = 0; j < C; ++j) { a += sA[i][j]*f[j]; la += sAL[i][j]*f[j]; }
            num[i] = r[i]*a; S += num[i]; likA += r[i]*la;
        }
        const float invS = frcp(S);
        float likE = 0.f;
        #pragma unroll
        for (int i = 0; i < C; ++i) {
            const float e2 = num[i]*invS;
            if (eout) eout[i] = e2;
            likE += e2 * lgB[i][xv];
        }
        return likA + likE;
    };

    float lik = 0.f;
    if (tid == 0) {                              // root: eps*(logPi + log emit)
        const int xr = x[base];
        #pragma unroll
        for (int c = 0; c < C; ++c) lik += buf[c] * (lgpi[c] + lgB[c][xr]);
    }
    for (int d = 1; d <= 8; ++d) {
        if (tid < (1 << d)) {
            const int v = (1 << d) - 1 + tid, pa = (v - 1) >> 1;
            float epa[C], r[C], eo[C];
            #pragma unroll
            for (int j = 0; j < C; ++j) epa[j] = buf[pa*PAD + j];
            #pragma unroll
            for (int i = 0; i < C; ++i) r[i] = buf[v*PAD + i];
            lik += child_node(r, epa, x[base + v], eo);
            #pragma unroll
            for (int i = 0; i < C; ++i) buf[v*PAD + i] = eo[i];
        }
        __syncthreads();
    }
    {   // subtree: node s then its two leaves, all in registers
        const int pas = 255 + (tid >> 1);
        float epa[C], es[C];
        #pragma unroll
        for (int j = 0; j < C; ++j) epa[j] = buf[pas*PAD + j];
        lik += child_node(rs, epa, xs, es);
        lik += child_node(r1, es, x1, nullptr);
        lik += child_node(r2, es, x2, nullptr);
    }

    // ---------------- reduce lik over block ----------------
    #pragma unroll
    for (int off = 32; off; off >>= 1) lik += __shfl_xor(lik, off, 64);
    if ((tid & 63) == 0) red8[tid >> 6] = lik;
    __syncthreads();
    if (tid == 0) {
        float acc = 0.f;
        #pragma unroll
        for (int w = 0; w < BLOCK/64; ++w) acc += red8[w];
        out[t*G + g] = -acc;
    }
}

extern "C" void kernel_launch(void* const* d_in, const int* in_sizes, int n_in,
                              void* d_out, int out_size, void* d_ws, size_t ws_size,
                              hipStream_t stream) {
    const float* A  = (const float*)d_in[0];
    const float* B  = (const float*)d_in[1];
    const float* Pi = (const float*)d_in[2];
    const int*   x  = (const int*)d_in[3];
    float* out = (float*)d_out;
    htmm_kernel<<<NTREES * G, BLOCK, 0, stream>>>(A, B, Pi, x, out);
}

// Round 3
// 120.151 us; speedup vs baseline: 1.0047x; 1.0047x over previous
//
#include <hip/hip_runtime.h>

// TopDownHTMM fused forward, v3.
// v2 post-mortem: the pass-3 lambda (raw float* args, nullable eout) defeated
// SROA -> per-thread arrays went to scratch (59 MB WRITE_SIZE, 225 B/thread).
// v3: same structure, but pass-3 node math is a __forceinline__ template fn
// taking array REFERENCES with if-constexpr eps-output -> everything in VGPRs.

#define NTREES 64
#define DEPTH  10
#define C      8
#define M      32
#define G      8
#define NPT    2047
#define PAD    9            // floats per node slot (odd -> conflict-light)
#define BLOCK  512
#define LNODES 1023         // nodes of levels 0..9

__device__ __forceinline__ float frcp(float v) { return __builtin_amdgcn_rcpf(v); }

// One child-node eps/likelihood step, fully register-resident.
// r: ratio beta/prior of node; epa: eps of parent; xv: symbol at node.
// Returns lik contribution; if WEPS, writes eps of node into eout.
template<bool WEPS>
__device__ __forceinline__ float child_node(const float (&sA)[C][C],
                                            const float (&sAL)[C][C],
                                            const float (&lgB)[C][M],
                                            const float (&r)[C],
                                            const float (&epa)[C],
                                            int xv,
                                            float (&eout)[C])
{
    float f[C];
    #pragma unroll
    for (int j = 0; j < C; ++j) {
        float tb = 0.f;
        #pragma unroll
        for (int i = 0; i < C; ++i) tb += sA[i][j] * r[i];
        f[j] = epa[j] * frcp(tb);
    }
    float S = 0.f, likA = 0.f, num[C];
    #pragma unroll
    for (int i = 0; i < C; ++i) {
        float a = 0.f, la = 0.f;
        #pragma unroll
        for (int j = 0; j < C; ++j) { a += sA[i][j] * f[j]; la += sAL[i][j] * f[j]; }
        num[i] = r[i] * a;
        S     += num[i];
        likA  += r[i] * la;
    }
    const float invS = frcp(S);
    float likE = 0.f;
    #pragma unroll
    for (int i = 0; i < C; ++i) {
        const float e2 = num[i] * invS;
        if constexpr (WEPS) eout[i] = e2;
        likE += e2 * lgB[i][xv];
    }
    return likA + likE;
}

__global__ __launch_bounds__(BLOCK, 4)
void htmm_kernel(const float* __restrict__ A,   // (C,C,G)
                 const float* __restrict__ B,   // (C,M,G)
                 const float* __restrict__ Pi,  // (C,G)
                 const int*   __restrict__ x,   // (DIM,)
                 float* __restrict__ out)       // (NTREES,G)
{
    __shared__ float buf[LNODES * PAD];         // 36,828 B
    __shared__ float sA[C][C], sAL[C][C];       // softmax_i A ; sA*log(sA)
    __shared__ float sB[C][M], lgB[C][M];
    __shared__ float spi[C],  lgpi[C];
    __shared__ float bls[C];                    // per-row logsumexp of B
    __shared__ float red8[BLOCK / 64];

    const int b   = blockIdx.x;
    const int t   = b >> 3;
    const int g   = b & 7;
    const int tid = threadIdx.x;
    const int base = t * NPT;

    // ---------------- phase 1: row stats ----------------
    if (tid < C) {                               // A column j: softmax over i
        const int j = tid;
        float w[C]; float mx = -1e30f;
        #pragma unroll
        for (int i = 0; i < C; ++i) { w[i] = A[(i*C + j)*G + g]; mx = fmaxf(mx, w[i]); }
        float s = 0.f; float e[C];
        #pragma unroll
        for (int i = 0; i < C; ++i) { e[i] = expf(w[i] - mx); s += e[i]; }
        const float inv = 1.f / s, ls = logf(s);
        #pragma unroll
        for (int i = 0; i < C; ++i) {
            const float sm = e[i] * inv;
            sA[i][j]  = sm;
            sAL[i][j] = sm * ((w[i] - mx) - ls);
        }
    } else if (tid == 8) {                       // Pi softmax
        float w[C]; float mx = -1e30f;
        #pragma unroll
        for (int c = 0; c < C; ++c) { w[c] = Pi[c*G + g]; mx = fmaxf(mx, w[c]); }
        float s = 0.f; float e[C];
        #pragma unroll
        for (int c = 0; c < C; ++c) { e[c] = expf(w[c] - mx); s += e[c]; }
        const float inv = 1.f / s, ls = logf(s);
        #pragma unroll
        for (int c = 0; c < C; ++c) { spi[c] = e[c]*inv; lgpi[c] = (w[c]-mx) - ls; }
    } else if (tid >= 64 && tid < 64 + C) {      // B row c: logsumexp
        const int c = tid - 64;
        float mx = -1e30f;
        for (int m = 0; m < M; ++m) mx = fmaxf(mx, B[(c*M + m)*G + g]);
        float s = 0.f;
        for (int m = 0; m < M; ++m) s += expf(B[(c*M + m)*G + g] - mx);
        bls[c] = mx + logf(s);
    }
    __syncthreads();

    // ---------------- phase 2: B softmax wide + root prior ----------------
    if (tid < C * M) {                           // 256 threads: one (c,m) each
        const int c = tid >> 5, m = tid & 31;
        const float d0 = B[(c*M + m)*G + g] - bls[c];
        lgB[c][m] = d0;
        sB[c][m]  = expf(d0);
    }
    if (tid == 320) {
        #pragma unroll
        for (int i = 0; i < C; ++i) buf[i] = spi[i];
    }
    __syncthreads();

    // ---------------- pass 1: prior, LDS levels 1..8 ----------------
    // both children share the same prior -> one matvec per parent
    for (int d = 1; d <= 8; ++d) {
        const int half = 1 << (d - 1);
        if (tid < half) {
            const int u = half - 1 + tid;        // parent (level d-1)
            const int cb = 2*u + 1;
            float p[C];
            #pragma unroll
            for (int j = 0; j < C; ++j) p[j] = buf[u*PAD + j];
            #pragma unroll
            for (int i = 0; i < C; ++i) {
                float acc = 0.f;
                #pragma unroll
                for (int j = 0; j < C; ++j) acc += sA[i][j] * p[j];
                buf[cb*PAD + i]       = acc;
                buf[(cb + 1)*PAD + i] = acc;
            }
        }
        __syncthreads();
    }

    // ---------------- pass 1: subtree (levels 9,10) in registers ----------------
    const int s  = 511 + tid;                    // owned level-9 node (local idx)
    const int xs = x[base + s];
    const int x1 = x[base + 2*s + 1];
    const int x2 = x[base + 2*s + 2];

    float ps[C], pc[C];                          // prior of s; prior of both leaves
    {
        const int pas = 255 + (tid >> 1);
        float pp[C];
        #pragma unroll
        for (int j = 0; j < C; ++j) pp[j] = buf[pas*PAD + j];
        #pragma unroll
        for (int i = 0; i < C; ++i) {
            float a = 0.f;
            #pragma unroll
            for (int j = 0; j < C; ++j) a += sA[i][j] * pp[j];
            ps[i] = a;
        }
        #pragma unroll
        for (int i = 0; i < C; ++i) {
            float a = 0.f;
            #pragma unroll
            for (int j = 0; j < C; ++j) a += sA[i][j] * ps[j];
            pc[i] = a;
        }
    }

    // ---------------- pass 2: subtree beta ratios in registers ----------------
    float rs[C], r1[C], r2[C];
    {
        float Z1 = 0.f, Z2 = 0.f;
        #pragma unroll
        for (int i = 0; i < C; ++i) {
            r1[i] = sB[i][x1]; Z1 += pc[i] * r1[i];
            r2[i] = sB[i][x2]; Z2 += pc[i] * r2[i];
        }
        const float i1 = frcp(Z1), i2 = frcp(Z2);
        #pragma unroll
        for (int i = 0; i < C; ++i) { r1[i] *= i1; r2[i] *= i2; }
        float Z = 0.f;
        #pragma unroll
        for (int j = 0; j < C; ++j) {
            float a1 = 0.f, a2 = 0.f;
            #pragma unroll
            for (int i = 0; i < C; ++i) { a1 += sA[i][j]*r1[i]; a2 += sA[i][j]*r2[i]; }
            rs[j] = sB[j][xs] * (a1 * a2);
            Z += ps[j] * rs[j];
        }
        const float iz = frcp(Z);
        #pragma unroll
        for (int j = 0; j < C; ++j) { rs[j] *= iz; buf[s*PAD + j] = rs[j]; }
    }
    __syncthreads();

    // ---------------- pass 2: LDS levels 8..0 ----------------
    for (int d = 8; d >= 0; --d) {
        if (tid < (1 << d)) {
            const int u = (1 << d) - 1 + tid;
            const int c1 = 2*u + 1;
            float rr1[C], rr2[C];
            #pragma unroll
            for (int i = 0; i < C; ++i) { rr1[i] = buf[c1*PAD + i]; rr2[i] = buf[(c1+1)*PAD + i]; }
            const int xu = x[base + u];
            float pr[C], ep[C]; float Z = 0.f;
            #pragma unroll
            for (int j = 0; j < C; ++j) {
                float a1 = 0.f, a2 = 0.f;
                #pragma unroll
                for (int i = 0; i < C; ++i) { a1 += sA[i][j]*rr1[i]; a2 += sA[i][j]*rr2[i]; }
                ep[j] = sB[j][xu] * (a1 * a2);
                pr[j] = buf[u*PAD + j];
                Z += pr[j] * ep[j];
            }
            const float iz = frcp(Z);
            if (d) {
                #pragma unroll
                for (int j = 0; j < C; ++j) buf[u*PAD + j] = ep[j]*iz;     // ratio
            } else {
                #pragma unroll
                for (int j = 0; j < C; ++j) buf[j] = pr[j]*ep[j]*iz;       // eps root
            }
        }
        __syncthreads();
    }

    // ---------------- pass 3: eps + likelihood ----------------
    float lik = 0.f;
    if (tid == 0) {                              // root: eps*(logPi + log emit)
        const int xr = x[base];
        #pragma unroll
        for (int c = 0; c < C; ++c) lik += buf[c] * (lgpi[c] + lgB[c][xr]);
    }
    for (int d = 1; d <= 8; ++d) {
        if (tid < (1 << d)) {
            const int v = (1 << d) - 1 + tid, pa = (v - 1) >> 1;
            float epa[C], r[C], eo[C];
            #pragma unroll
            for (int j = 0; j < C; ++j) epa[j] = buf[pa*PAD + j];
            #pragma unroll
            for (int i = 0; i < C; ++i) r[i] = buf[v*PAD + i];
            lik += child_node<true>(sA, sAL, lgB, r, epa, x[base + v], eo);
            #pragma unroll
            for (int i = 0; i < C; ++i) buf[v*PAD + i] = eo[i];
        }
        __syncthreads();
    }
    {   // subtree: node s then its two leaves, all in registers
        const int pas = 255 + (tid >> 1);
        float epa[C], es[C], dummy[C];
        #pragma unroll
        for (int j = 0; j < C; ++j) epa[j] = buf[pas*PAD + j];
        lik += child_node<true >(sA, sAL, lgB, rs, epa, xs, es);
        lik += child_node<false>(sA, sAL, lgB, r1, es,  x1, dummy);
        lik += child_node<false>(sA, sAL, lgB, r2, es,  x2, dummy);
    }

    // ---------------- reduce lik over block ----------------
    #pragma unroll
    for (int off = 32; off; off >>= 1) lik += __shfl_xor(lik, off, 64);
    if ((tid & 63) == 0) red8[tid >> 6] = lik;
    __syncthreads();
    if (tid == 0) {
        float acc = 0.f;
        #pragma unroll
        for (int w = 0; w < BLOCK/64; ++w) acc += red8[w];
        out[t*G + g] = -acc;
    }
}

extern "C" void kernel_launch(void* const* d_in, const int* in_sizes, int n_in,
                              void* d_out, int out_size, void* d_ws, size_t ws_size,
                              hipStream_t stream) {
    const float* A  = (const float*)d_in[0];
    const float* B  = (const float*)d_in[1];
    const float* Pi = (const float*)d_in[2];
    const int*   x  = (const int*)d_in[3];
    float* out = (float*)d_out;
    htmm_kernel<<<NTREES * G, BLOCK, 0, stream>>>(A, B, Pi, x, out);
}

// Round 7
// 116.987 us; speedup vs baseline: 1.0319x; 1.0270x over previous
//
#include <hip/hip_runtime.h>

// TopDownHTMM fused forward, v4 (third resubmit — rounds 4-6 were GPU
// acquisition timeouts; this kernel has never run).
// v3 post-mortem: __launch_bounds__(512,4) capped VGPRs at 64; the per-thread
// working set (~100+ regs: ps/pc/rs/r1/r2 + child_node temps) spilled ~225 B
// per thread -> 110 MB scratch HBM traffic = the whole 52 us runtime.
// v4: identical structure, __launch_bounds__(512,2) -> VGPR cap 256, no spill.

#define NTREES 64
#define DEPTH  10
#define C      8
#define M      32
#define G      8
#define NPT    2047
#define PAD    9            // floats per node slot (odd -> conflict-light)
#define BLOCK  512
#define LNODES 1023         // nodes of levels 0..9

__device__ __forceinline__ float frcp(float v) { return __builtin_amdgcn_rcpf(v); }

// One child-node eps/likelihood step, fully register-resident.
// r: ratio beta/prior of node; epa: eps of parent; xv: symbol at node.
// Returns lik contribution; if WEPS, writes eps of node into eout.
template<bool WEPS>
__device__ __forceinline__ float child_node(const float (&sA)[C][C],
                                            const float (&sAL)[C][C],
                                            const float (&lgB)[C][M],
                                            const float (&r)[C],
                                            const float (&epa)[C],
                                            int xv,
                                            float (&eout)[C])
{
    float f[C];
    #pragma unroll
    for (int j = 0; j < C; ++j) {
        float tb = 0.f;
        #pragma unroll
        for (int i = 0; i < C; ++i) tb += sA[i][j] * r[i];
        f[j] = epa[j] * frcp(tb);
    }
    float S = 0.f, likA = 0.f, num[C];
    #pragma unroll
    for (int i = 0; i < C; ++i) {
        float a = 0.f, la = 0.f;
        #pragma unroll
        for (int j = 0; j < C; ++j) { a += sA[i][j] * f[j]; la += sAL[i][j] * f[j]; }
        num[i] = r[i] * a;
        S     += num[i];
        likA  += r[i] * la;
    }
    const float invS = frcp(S);
    float likE = 0.f;
    #pragma unroll
    for (int i = 0; i < C; ++i) {
        const float e2 = num[i] * invS;
        if constexpr (WEPS) eout[i] = e2;
        likE += e2 * lgB[i][xv];
    }
    return likA + likE;
}

__global__ __launch_bounds__(BLOCK, 2)
void htmm_kernel(const float* __restrict__ A,   // (C,C,G)
                 const float* __restrict__ B,   // (C,M,G)
                 const float* __restrict__ Pi,  // (C,G)
                 const int*   __restrict__ x,   // (DIM,)
                 float* __restrict__ out)       // (NTREES,G)
{
    __shared__ float buf[LNODES * PAD];         // 36,828 B
    __shared__ float sA[C][C], sAL[C][C];       // softmax_i A ; sA*log(sA)
    __shared__ float sB[C][M], lgB[C][M];
    __shared__ float spi[C],  lgpi[C];
    __shared__ float bls[C];                    // per-row logsumexp of B
    __shared__ float red8[BLOCK / 64];

    const int b   = blockIdx.x;
    const int t   = b >> 3;
    const int g   = b & 7;
    const int tid = threadIdx.x;
    const int base = t * NPT;

    // ---------------- phase 1: row stats ----------------
    if (tid < C) {                               // A column j: softmax over i
        const int j = tid;
        float w[C]; float mx = -1e30f;
        #pragma unroll
        for (int i = 0; i < C; ++i) { w[i] = A[(i*C + j)*G + g]; mx = fmaxf(mx, w[i]); }
        float s = 0.f; float e[C];
        #pragma unroll
        for (int i = 0; i < C; ++i) { e[i] = expf(w[i] - mx); s += e[i]; }
        const float inv = 1.f / s, ls = logf(s);
        #pragma unroll
        for (int i = 0; i < C; ++i) {
            const float sm = e[i] * inv;
            sA[i][j]  = sm;
            sAL[i][j] = sm * ((w[i] - mx) - ls);
        }
    } else if (tid == 8) {                       // Pi softmax
        float w[C]; float mx = -1e30f;
        #pragma unroll
        for (int c = 0; c < C; ++c) { w[c] = Pi[c*G + g]; mx = fmaxf(mx, w[c]); }
        float s = 0.f; float e[C];
        #pragma unroll
        for (int c = 0; c < C; ++c) { e[c] = expf(w[c] - mx); s += e[c]; }
        const float inv = 1.f / s, ls = logf(s);
        #pragma unroll
        for (int c = 0; c < C; ++c) { spi[c] = e[c]*inv; lgpi[c] = (w[c]-mx) - ls; }
    } else if (tid >= 64 && tid < 64 + C) {      // B row c: logsumexp
        const int c = tid - 64;
        float mx = -1e30f;
        for (int m = 0; m < M; ++m) mx = fmaxf(mx, B[(c*M + m)*G + g]);
        float s = 0.f;
        for (int m = 0; m < M; ++m) s += expf(B[(c*M + m)*G + g] - mx);
        bls[c] = mx + logf(s);
    }
    __syncthreads();

    // ---------------- phase 2: B softmax wide + root prior ----------------
    if (tid < C * M) {                           // 256 threads: one (c,m) each
        const int c = tid >> 5, m = tid & 31;
        const float d0 = B[(c*M + m)*G + g] - bls[c];
        lgB[c][m] = d0;
        sB[c][m]  = expf(d0);
    }
    if (tid == 320) {
        #pragma unroll
        for (int i = 0; i < C; ++i) buf[i] = spi[i];
    }
    __syncthreads();

    // ---------------- pass 1: prior, LDS levels 1..8 ----------------
    // both children share the same prior -> one matvec per parent
    for (int d = 1; d <= 8; ++d) {
        const int half = 1 << (d - 1);
        if (tid < half) {
            const int u = half - 1 + tid;        // parent (level d-1)
            const int cb = 2*u + 1;
            float p[C];
            #pragma unroll
            for (int j = 0; j < C; ++j) p[j] = buf[u*PAD + j];
            #pragma unroll
            for (int i = 0; i < C; ++i) {
                float acc = 0.f;
                #pragma unroll
                for (int j = 0; j < C; ++j) acc += sA[i][j] * p[j];
                buf[cb*PAD + i]       = acc;
                buf[(cb + 1)*PAD + i] = acc;
            }
        }
        __syncthreads();
    }

    // ---------------- pass 1: subtree (levels 9,10) in registers ----------------
    const int s  = 511 + tid;                    // owned level-9 node (local idx)
    const int xs = x[base + s];
    const int x1 = x[base + 2*s + 1];
    const int x2 = x[base + 2*s + 2];

    float ps[C], pc[C];                          // prior of s; prior of both leaves
    {
        const int pas = 255 + (tid >> 1);
        float pp[C];
        #pragma unroll
        for (int j = 0; j < C; ++j) pp[j] = buf[pas*PAD + j];
        #pragma unroll
        for (int i = 0; i < C; ++i) {
            float a = 0.f;
            #pragma unroll
            for (int j = 0; j < C; ++j) a += sA[i][j] * pp[j];
            ps[i] = a;
        }
        #pragma unroll
        for (int i = 0; i < C; ++i) {
            float a = 0.f;
            #pragma unroll
            for (int j = 0; j < C; ++j) a += sA[i][j] * ps[j];
            pc[i] = a;
        }
    }

    // ---------------- pass 2: subtree beta ratios in registers ----------------
    float rs[C], r1[C], r2[C];
    {
        float Z1 = 0.f, Z2 = 0.f;
        #pragma unroll
        for (int i = 0; i < C; ++i) {
            r1[i] = sB[i][x1]; Z1 += pc[i] * r1[i];
            r2[i] = sB[i][x2]; Z2 += pc[i] * r2[i];
        }
        const float i1 = frcp(Z1), i2 = frcp(Z2);
        #pragma unroll
        for (int i = 0; i < C; ++i) { r1[i] *= i1; r2[i] *= i2; }
        float Z = 0.f;
        #pragma unroll
        for (int j = 0; j < C; ++j) {
            float a1 = 0.f, a2 = 0.f;
            #pragma unroll
            for (int i = 0; i < C; ++i) { a1 += sA[i][j]*r1[i]; a2 += sA[i][j]*r2[i]; }
            rs[j] = sB[j][xs] * (a1 * a2);
            Z += ps[j] * rs[j];
        }
        const float iz = frcp(Z);
        #pragma unroll
        for (int j = 0; j < C; ++j) { rs[j] *= iz; buf[s*PAD + j] = rs[j]; }
    }
    __syncthreads();

    // ---------------- pass 2: LDS levels 8..0 ----------------
    for (int d = 8; d >= 0; --d) {
        if (tid < (1 << d)) {
            const int u = (1 << d) - 1 + tid;
            const int c1 = 2*u + 1;
            float rr1[C], rr2[C];
            #pragma unroll
            for (int i = 0; i < C; ++i) { rr1[i] = buf[c1*PAD + i]; rr2[i] = buf[(c1+1)*PAD + i]; }
            const int xu = x[base + u];
            float pr[C], ep[C]; float Z = 0.f;
            #pragma unroll
            for (int j = 0; j < C; ++j) {
                float a1 = 0.f, a2 = 0.f;
                #pragma unroll
                for (int i = 0; i < C; ++i) { a1 += sA[i][j]*rr1[i]; a2 += sA[i][j]*rr2[i]; }
                ep[j] = sB[j][xu] * (a1 * a2);
                pr[j] = buf[u*PAD + j];
                Z += pr[j] * ep[j];
            }
            const float iz = frcp(Z);
            if (d) {
                #pragma unroll
                for (int j = 0; j < C; ++j) buf[u*PAD + j] = ep[j]*iz;     // ratio
            } else {
                #pragma unroll
                for (int j = 0; j < C; ++j) buf[j] = pr[j]*ep[j]*iz;       // eps root
            }
        }
        __syncthreads();
    }

    // ---------------- pass 3: eps + likelihood ----------------
    float lik = 0.f;
    if (tid == 0) {                              // root: eps*(logPi + log emit)
        const int xr = x[base];
        #pragma unroll
        for (int c = 0; c < C; ++c) lik += buf[c] * (lgpi[c] + lgB[c][xr]);
    }
    for (int d = 1; d <= 8; ++d) {
        if (tid < (1 << d)) {
            const int v = (1 << d) - 1 + tid, pa = (v - 1) >> 1;
            float epa[C], r[C], eo[C];
            #pragma unroll
            for (int j = 0; j < C; ++j) epa[j] = buf[pa*PAD + j];
            #pragma unroll
            for (int i = 0; i < C; ++i) r[i] = buf[v*PAD + i];
            lik += child_node<true>(sA, sAL, lgB, r, epa, x[base + v], eo);
            #pragma unroll
            for (int i = 0; i < C; ++i) buf[v*PAD + i] = eo[i];
        }
        __syncthreads();
    }
    {   // subtree: node s then its two leaves, all in registers
        const int pas = 255 + (tid >> 1);
        float epa[C], es[C], dummy[C];
        #pragma unroll
        for (int j = 0; j < C; ++j) epa[j] = buf[pas*PAD + j];
        lik += child_node<true >(sA, sAL, lgB, rs, epa, xs, es);
        lik += child_node<false>(sA, sAL, lgB, r1, es,  x1, dummy);
        lik += child_node<false>(sA, sAL, lgB, r2, es,  x2, dummy);
    }

    // ---------------- reduce lik over block ----------------
    #pragma unroll
    for (int off = 32; off; off >>= 1) lik += __shfl_xor(lik, off, 64);
    if ((tid & 63) == 0) red8[tid >> 6] = lik;
    __syncthreads();
    if (tid == 0) {
        float acc = 0.f;
        #pragma unroll
        for (int w = 0; w < BLOCK/64; ++w) acc += red8[w];
        out[t*G + g] = -acc;
    }
}

extern "C" void kernel_launch(void* const* d_in, const int* in_sizes, int n_in,
                              void* d_out, int out_size, void* d_ws, size_t ws_size,
                              hipStream_t stream) {
    const float* A  = (const float*)d_in[0];
    const float* B  = (const float*)d_in[1];
    const float* Pi = (const float*)d_in[2];
    const int*   x  = (const int*)d_in[3];
    float* out = (float*)d_out;
    htmm_kernel<<<NTREES * G, BLOCK, 0, stream>>>(A, B, Pi, x, out);
}